// Round 3
// baseline (99.628 us; speedup 1.0000x reference)
//
#include <hip/hip_runtime.h>

#define NG 512
#define NPX 262144
#define BLOCK 256
#define GTILE 4          // Gaussians per SGPR tile (double-buffered)
#define PPT 2            // pixels per thread
#define HALFPX (NPX / 2) // 131072

#if __has_builtin(__builtin_amdgcn_exp2f)
  #define KSCALE 0.72134752044448170368f   /* 0.5 * log2(e) */
  #define EXPNEG(w) __builtin_amdgcn_exp2f(-(w))
#else
  #define KSCALE 0.5f
  #define EXPNEG(w) __expf(-(w))
#endif

// ---------------------------------------------------------------------------
// Prep kernel: fold rotation/scale/mean/alpha into 6 constants per Gaussian.
//   ga[n] = (p00, p01, -uoff, alpha)      (float4, 8 KB total)
//   gb[n] = (p11, -voff)                  (float2, 4 KB total)
// k*q = (p00*x + p01*y - uoff)^2 + (p11*y - voff)^2, k = 0.5*log2(e)
// ---------------------------------------------------------------------------
__global__ void gsplat_prep(const float* __restrict__ alphas,
                            const float* __restrict__ means,
                            const float* __restrict__ rotations,
                            const float* __restrict__ scales,
                            float4* __restrict__ ga,
                            float2* __restrict__ gb)
{
    int n = blockIdx.x * blockDim.x + threadIdx.x;
    if (n >= NG) return;

    float rot = rotations[n];
    float sth, cth;
    sincosf(rot, &sth, &cth);
    float s0 = scales[2 * n + 0];
    float s1 = scales[2 * n + 1];
    float r00 = s0 * cth, r01 = -s1 * sth;
    float r10 = s0 * sth, r11 =  s1 * cth;
    float Ar = r00 * r00 + r01 * r01;
    float Br = r00 * r10 + r01 * r11;
    float Dr = r10 * r10 + r11 * r11;
    float det = Ar * Dr - Br * Br;
    float kc00 =  KSCALE * Dr / det;
    float kc01 = -KSCALE * Br / det;
    float p00 = sqrtf(kc00);
    float p01 = kc01 / p00;
    float p11 = sqrtf(KSCALE / Dr);
    float mx = means[2 * n + 0];
    float my = means[2 * n + 1];
    float nuoff = -(p00 * mx + p01 * my);
    float nvoff = -(p11 * my);

    ga[n] = make_float4(p00, p01, nuoff, alphas[n]);
    gb[n] = make_float2(p11, nvoff);
}

// ---------------------------------------------------------------------------
// Main kernel: PPT=2 pixels per thread. Gaussian constants live in SGPRs
// (uniform s_load, double-buffered GTILE tiles, software prefetch). The
// pixel-independent addend constants (a.z, b.y) are materialized to VGPR
// once per Gaussian and shared by both pixels, so every fma reads <=1 SGPR.
// ---------------------------------------------------------------------------
__global__ __launch_bounds__(BLOCK)
void gsplat_main(const float* __restrict__ x,
                 const float4* __restrict__ ga,
                 const float2* __restrict__ gb,
                 float* __restrict__ out)
{
    int tid = blockIdx.x * BLOCK + threadIdx.x;
    float2 pv0 = ((const float2*)x)[tid];
    float2 pv1 = ((const float2*)x)[tid + HALFPX];
    float x0 = pv0.x, y0 = pv0.y;
    float x1 = pv1.x, y1 = pv1.y;

    float accA0 = 0.0f, accA1 = 0.0f;   // pixel 0, split by parity
    float accB0 = 0.0f, accB1 = 0.0f;   // pixel 1, split by parity

    float4 ca[GTILE]; float2 cb[GTILE];   // current tile
    float4 na[GTILE]; float2 nb[GTILE];   // next tile (prefetch)

    #pragma unroll
    for (int j = 0; j < GTILE; ++j) { ca[j] = ga[j]; cb[j] = gb[j]; }

    #define COMPUTE_TILE(A, B)                                                \
        _Pragma("unroll")                                                     \
        for (int j = 0; j < GTILE; ++j) {                                     \
            float czu = A[j].z;   /* shared s->v materialization */           \
            float czv = B[j].y;                                               \
            float u0 = fmaf(A[j].x, x0, fmaf(A[j].y, y0, czu));               \
            float v0 = fmaf(B[j].x, y0, czv);                                 \
            float w0 = fmaf(v0, v0, u0 * u0);                                 \
            float e0 = EXPNEG(w0);                                            \
            float u1 = fmaf(A[j].x, x1, fmaf(A[j].y, y1, czu));               \
            float v1 = fmaf(B[j].x, y1, czv);                                 \
            float w1 = fmaf(v1, v1, u1 * u1);                                 \
            float e1 = EXPNEG(w1);                                            \
            if (j & 1) { accA1 = fmaf(A[j].w, e0, accA1);                     \
                         accB1 = fmaf(A[j].w, e1, accB1); }                   \
            else       { accA0 = fmaf(A[j].w, e0, accA0);                     \
                         accB0 = fmaf(A[j].w, e1, accB0); }                   \
        }

    for (int t = 0; t < NG; t += 2 * GTILE) {
        // prefetch tile t+GTILE while computing tile t
        #pragma unroll
        for (int j = 0; j < GTILE; ++j) {
            int n = (t + GTILE + j) & (NG - 1);
            na[j] = ga[n]; nb[j] = gb[n];
        }
        COMPUTE_TILE(ca, cb)

        // prefetch tile t+2*GTILE while computing tile t+GTILE
        #pragma unroll
        for (int j = 0; j < GTILE; ++j) {
            int n = (t + 2 * GTILE + j) & (NG - 1);
            ca[j] = ga[n]; cb[j] = gb[n];
        }
        COMPUTE_TILE(na, nb)
    }
    #undef COMPUTE_TILE

    out[tid]          = accA0 + accA1;
    out[tid + HALFPX] = accB0 + accB1;
}

extern "C" void kernel_launch(void* const* d_in, const int* in_sizes, int n_in,
                              void* d_out, int out_size, void* d_ws, size_t ws_size,
                              hipStream_t stream) {
    const float* x         = (const float*)d_in[0];
    const float* alphas    = (const float*)d_in[1];
    const float* means     = (const float*)d_in[2];
    const float* rotations = (const float*)d_in[3];
    const float* scales    = (const float*)d_in[4];
    float* out = (float*)d_out;

    float4* ga = (float4*)d_ws;                          // 512 * 16 B = 8 KB
    float2* gb = (float2*)((char*)d_ws + NG * 16);       // 512 *  8 B = 4 KB

    gsplat_prep<<<(NG + 255) / 256, 256, 0, stream>>>(alphas, means, rotations, scales, ga, gb);

    int grid = NPX / (BLOCK * PPT);  // 512 blocks -> 2 blocks/CU, 8 waves/CU
    gsplat_main<<<grid, BLOCK, 0, stream>>>(x, ga, gb, out);
}

// Round 4
// 89.800 us; speedup vs baseline: 1.1095x; 1.1095x over previous
//
#include <hip/hip_runtime.h>

#define NG 512
#define NPX 262144
#define BLOCK 256
#define GTILE 4          // Gaussians per SGPR tile (double-buffered)
#define PPT 2            // pixels per thread
#define GSPLIT 4         // Gaussian-loop split across blocks
#define GPB (NG / GSPLIT)    // 128 Gaussians per block
#define HALFPX (NPX / 2)     // 131072

#if __has_builtin(__builtin_amdgcn_exp2f)
  #define KSCALE 0.72134752044448170368f   /* 0.5 * log2(e) */
  #define EXPNEG(w) __builtin_amdgcn_exp2f(-(w))
#else
  #define KSCALE 0.5f
  #define EXPNEG(w) __expf(-(w))
#endif

// ---------------------------------------------------------------------------
// Prep kernel (grid covers NPX threads):
//   - zeroes out[] (main accumulates into it with atomics)
//   - threads 0..NG-1 fold rotation/scale/mean/alpha into 6 constants:
//       ga[n] = (p00, p01, -uoff, alpha)   gb[n] = (p11, -voff)
//     k*q = (p00*x + p01*y - uoff)^2 + (p11*y - voff)^2, k = 0.5*log2(e)
// ---------------------------------------------------------------------------
__global__ void gsplat_prep(const float* __restrict__ alphas,
                            const float* __restrict__ means,
                            const float* __restrict__ rotations,
                            const float* __restrict__ scales,
                            float4* __restrict__ ga,
                            float2* __restrict__ gb,
                            float* __restrict__ out)
{
    int t = blockIdx.x * blockDim.x + threadIdx.x;
    out[t] = 0.0f;
    if (t >= NG) return;
    int n = t;

    float rot = rotations[n];
    float sth, cth;
    sincosf(rot, &sth, &cth);
    float s0 = scales[2 * n + 0];
    float s1 = scales[2 * n + 1];
    float r00 = s0 * cth, r01 = -s1 * sth;
    float r10 = s0 * sth, r11 =  s1 * cth;
    float Ar = r00 * r00 + r01 * r01;
    float Br = r00 * r10 + r01 * r11;
    float Dr = r10 * r10 + r11 * r11;
    float det = Ar * Dr - Br * Br;
    float kc00 =  KSCALE * Dr / det;
    float kc01 = -KSCALE * Br / det;
    float p00 = sqrtf(kc00);
    float p01 = kc01 / p00;
    float p11 = sqrtf(KSCALE / Dr);
    float mx = means[2 * n + 0];
    float my = means[2 * n + 1];
    float nuoff = -(p00 * mx + p01 * my);
    float nvoff = -(p11 * my);

    ga[n] = make_float4(p00, p01, nuoff, alphas[n]);
    gb[n] = make_float2(p11, nvoff);
}

// ---------------------------------------------------------------------------
// Main kernel: 2048 blocks = 512 pixel-blocks x 4 Gaussian splits.
// Each block: PPT=2 pixels/thread over GPB=128 Gaussians. Constants live in
// SGPRs (uniform s_load, double-buffered GTILE tiles). The pixel-independent
// addends (a.z, b.y) are materialized to VGPR once per Gaussian and shared
// by both pixels, so every fma reads <=1 SGPR. Partials combined via
// atomicAdd (out pre-zeroed by prep; same-stream ordering guarantees).
// ---------------------------------------------------------------------------
__global__ __launch_bounds__(BLOCK)
void gsplat_main(const float* __restrict__ x,
                 const float4* __restrict__ ga,
                 const float2* __restrict__ gb,
                 float* __restrict__ out)
{
    int bid = blockIdx.x;
    int pixblk = bid >> 2;               // [0, 512)
    int gbase  = (bid & 3) * GPB;        // 0,128,256,384

    int tid = pixblk * BLOCK + threadIdx.x;   // [0, 131072)
    float2 pv0 = ((const float2*)x)[tid];
    float2 pv1 = ((const float2*)x)[tid + HALFPX];
    float x0 = pv0.x, y0 = pv0.y;
    float x1 = pv1.x, y1 = pv1.y;

    float accA0 = 0.0f, accA1 = 0.0f;   // pixel 0, split by parity
    float accB0 = 0.0f, accB1 = 0.0f;   // pixel 1, split by parity

    float4 ca[GTILE]; float2 cb[GTILE];   // current tile
    float4 na[GTILE]; float2 nb[GTILE];   // next tile (prefetch)

    #pragma unroll
    for (int j = 0; j < GTILE; ++j) { ca[j] = ga[gbase + j]; cb[j] = gb[gbase + j]; }

    #define COMPUTE_TILE(A, B)                                                \
        _Pragma("unroll")                                                     \
        for (int j = 0; j < GTILE; ++j) {                                     \
            float czu = A[j].z;   /* shared s->v materialization */           \
            float czv = B[j].y;                                               \
            float u0 = fmaf(A[j].x, x0, fmaf(A[j].y, y0, czu));               \
            float v0 = fmaf(B[j].x, y0, czv);                                 \
            float w0 = fmaf(v0, v0, u0 * u0);                                 \
            float e0 = EXPNEG(w0);                                            \
            float u1 = fmaf(A[j].x, x1, fmaf(A[j].y, y1, czu));               \
            float v1 = fmaf(B[j].x, y1, czv);                                 \
            float w1 = fmaf(v1, v1, u1 * u1);                                 \
            float e1 = EXPNEG(w1);                                            \
            if (j & 1) { accA1 = fmaf(A[j].w, e0, accA1);                     \
                         accB1 = fmaf(A[j].w, e1, accB1); }                   \
            else       { accA0 = fmaf(A[j].w, e0, accA0);                     \
                         accB0 = fmaf(A[j].w, e1, accB0); }                   \
        }

    for (int t = 0; t < GPB; t += 2 * GTILE) {
        // prefetch tile t+GTILE while computing tile t
        #pragma unroll
        for (int j = 0; j < GTILE; ++j) {
            int n = gbase + ((t + GTILE + j) & (GPB - 1));
            na[j] = ga[n]; nb[j] = gb[n];
        }
        COMPUTE_TILE(ca, cb)

        // prefetch tile t+2*GTILE while computing tile t+GTILE
        #pragma unroll
        for (int j = 0; j < GTILE; ++j) {
            int n = gbase + ((t + 2 * GTILE + j) & (GPB - 1));
            ca[j] = ga[n]; cb[j] = gb[n];
        }
        COMPUTE_TILE(na, nb)
    }
    #undef COMPUTE_TILE

    atomicAdd(&out[tid],          accA0 + accA1);
    atomicAdd(&out[tid + HALFPX], accB0 + accB1);
}

extern "C" void kernel_launch(void* const* d_in, const int* in_sizes, int n_in,
                              void* d_out, int out_size, void* d_ws, size_t ws_size,
                              hipStream_t stream) {
    const float* x         = (const float*)d_in[0];
    const float* alphas    = (const float*)d_in[1];
    const float* means     = (const float*)d_in[2];
    const float* rotations = (const float*)d_in[3];
    const float* scales    = (const float*)d_in[4];
    float* out = (float*)d_out;

    float4* ga = (float4*)d_ws;                          // 512 * 16 B = 8 KB
    float2* gb = (float2*)((char*)d_ws + NG * 16);       // 512 *  8 B = 4 KB

    // zero out[] + build per-Gaussian constants
    gsplat_prep<<<NPX / BLOCK, BLOCK, 0, stream>>>(alphas, means, rotations, scales, ga, gb, out);

    // 2048 blocks = 8 blocks/CU -> 32 waves/CU (full residency, 8 waves/SIMD)
    int grid = (NPX / (BLOCK * PPT)) * GSPLIT;
    gsplat_main<<<grid, BLOCK, 0, stream>>>(x, ga, gb, out);
}